// Round 13
// baseline (341.793 us; speedup 1.0000x reference)
//
#include <hip/hip_runtime.h>

// ---------------------------------------------------------------------------
// GraphEmbedding pipeline for MI355X (gfx950) — round 13:
//  - k_attn: split-K=8, 128-thread blocks (2 waves x 32q), grid 4096
//    (16 blocks/CU = 100% static occupancy), single P buffer,
//    fp32 atomicAdd accumulation of O and lsum (no OTp partials)
//  - k_prep zeroes O/lp; k_proj stages A directly from O/lp
//  - rest identical to round 12
// N=4096, IN_DIM=256, HID=256, OUT=128, HEADS=8, HD=32, E=65536
// ---------------------------------------------------------------------------

#define NN 4096
#define NE 65536

typedef unsigned short u16;
typedef unsigned int u32;
typedef __attribute__((ext_vector_type(8))) short short8;   // 8 x bf16
typedef __attribute__((ext_vector_type(4))) short bhalf4;   // 4 x bf16
typedef __attribute__((ext_vector_type(4))) float floatx4;

#define QSCALE (0.17677669529663687f * 1.4426950408889634f)  // hd^-0.5 * log2(e)

__device__ __forceinline__ u32 fasu(float x) {
  union { float f; u32 u; } v; v.f = x; return v.u;
}
__device__ __forceinline__ float bfasf(u16 h) {
  union { float f; u32 u; } v; v.u = ((u32)h) << 16; return v.f;
}
__device__ __forceinline__ u16 f2bf(float x) {
  u32 u = fasu(x);
  return (u16)((u + 0x7FFFu + ((u >> 16) & 1u)) >> 16);
}
// pack two fp32 -> bf16 pair (round-half-up) in one v_perm
__device__ __forceinline__ u32 pkbf(float lo, float hi) {
  return __builtin_amdgcn_perm(fasu(hi) + 0x8000u, fasu(lo) + 0x8000u,
                               0x07060302u);
}

// ---------------------------------------------------------------------------
// Prep: fold BN into conv weights; convert all GEMM weights to bf16 [o][c];
// zero deg/cnt, O accumulator, lp accumulator.
// ---------------------------------------------------------------------------
__global__ __launch_bounds__(256) void k_prep(
    const float* __restrict__ conv_w, const float* __restrict__ conv_b,
    const float* __restrict__ bn_g, const float* __restrict__ bn_b,
    const float* __restrict__ bn_m, const float* __restrict__ bn_v,
    const float* __restrict__ qkv_w, const float* __restrict__ proj_w,
    const float* __restrict__ gcn1_w, const float* __restrict__ gcn2_w,
    const float* __restrict__ sc_w,
    u16* __restrict__ WBc, float* __restrict__ bfold,
    u16* __restrict__ WBqkv, u16* __restrict__ WBproj,
    u16* __restrict__ WB1, u16* __restrict__ WB2, u16* __restrict__ WBsc,
    float* __restrict__ deg, int* __restrict__ cnt,
    float* __restrict__ Oacc, float* __restrict__ lp) {
  int g = blockIdx.x * 256 + threadIdx.x;
  if (g < 4096) { deg[g] = 0.f; cnt[g] = 0; }
  for (int z = g; z < 1048576; z += 458752) Oacc[z] = 0.f;
  if (g < 32768) lp[g] = 0.f;
  if (g < 65536) {                      // conv fold: [o][c]
    int o = g >> 8;
    float alpha = bn_g[o] / sqrtf(bn_v[o] + 1e-5f);
    WBc[g] = f2bf(conv_w[g] * alpha);
    if ((g & 255) == 0) bfold[o] = (conv_b[o] - bn_m[o]) * alpha + bn_b[o];
  } else if (g < 262144) {
    int g2 = g - 65536;  WBqkv[g2] = f2bf(qkv_w[g2]);
  } else if (g < 327680) {
    int g3 = g - 262144; WBproj[g3] = f2bf(proj_w[g3]);
  } else if (g < 393216) {
    int g4 = g - 327680; WB1[g4] = f2bf(gcn1_w[g4]);
  } else if (g < 425984) {
    int g5 = g - 393216; WB2[g5] = f2bf(gcn2_w[g5]);
  } else if (g < 458752) {
    int g6 = g - 425984; WBsc[g6] = f2bf(sc_w[g6]);
  }
}

// ---------------------------------------------------------------------------
// Conv 1x1 + BN + relu + spatial mean, MFMA (round-11 version, unchanged).
// ---------------------------------------------------------------------------
__global__ __launch_bounds__(256, 3) void k_conv(const float* __restrict__ F,
    const u16* __restrict__ WB, const float* __restrict__ bfold,
    u16* __restrict__ x0b,
    const int* __restrict__ edges, const float* __restrict__ ew,
    int* __restrict__ cnt, float* __restrict__ deg) {
  __shared__ u16 smem[20480];           // 2 x (256 rows x 40 u16) = 40 KB
  int t = threadIdx.x, bx = blockIdx.x;

  if (bx >= 1024) {                     // fused k_count
    int i = (bx - 1024) * 256 + t;      // 0..2E-1
    int e = i & (NE - 1);
    int fwd = (i < NE);
    int a = edges[2 * e], b = edges[2 * e + 1];
    int row = fwd ? a : b;
    float v = ew[e];
    atomicAdd(&cnt[row], 1);
    atomicAdd(&deg[row], v);
    return;
  }

  int wv = t >> 6, ln = t & 63, lo = ln & 15, quad = ln >> 4;

  const float* Fn = F + (size_t)(bx * 4 + wv) * 4096;
  short8 afr[8];
#pragma unroll
  for (int half = 0; half < 2; ++half) {
    float tmp[32];
#pragma unroll
    for (int kc2 = 0; kc2 < 4; ++kc2) {
      int cb = (half * 4 + kc2) * 32 + quad * 8;
#pragma unroll
      for (int j = 0; j < 8; ++j)
        tmp[kc2 * 8 + j] = Fn[(cb + j) * 16 + lo];
    }
#pragma unroll
    for (int kc2 = 0; kc2 < 4; ++kc2)
#pragma unroll
      for (int j = 0; j < 8; ++j)
        afr[half * 4 + kc2][j] = (short)f2bf(tmp[kc2 * 8 + j]);
  }

#pragma unroll
  for (int i = 0; i < 4; ++i) {
    int u = i * 256 + t;
    int o = u >> 2, k16 = u & 3;
    short8 v = *(const short8*)(WB + o * 256 + k16 * 8);
    *(short8*)(&smem[o * 40 + k16 * 8]) = v;
  }

  floatx4 acc[16];
#pragma unroll
  for (int i = 0; i < 16; ++i) acc[i] = (floatx4){0.f, 0.f, 0.f, 0.f};

  __syncthreads();

  for (int kc = 0; kc < 8; ++kc) {
    int cur = kc & 1;
    u16* Bcur = smem + cur * 10240;
    u16* Bnxt = smem + (cur ^ 1) * 10240;
    short8 breg[4];
    if (kc < 7) {
#pragma unroll
      for (int i = 0; i < 4; ++i) {
        int u = i * 256 + t;
        int o = u >> 2, k16 = u & 3;
        breg[i] = *(const short8*)(WB + o * 256 + (kc + 1) * 32 + k16 * 8);
      }
    }
#pragma unroll
    for (int ct = 0; ct < 16; ++ct) {
      short8 bf = *(const short8*)(Bcur + (ct * 16 + lo) * 40 + quad * 8);
      acc[ct] = __builtin_amdgcn_mfma_f32_16x16x32_bf16(afr[kc], bf, acc[ct], 0, 0, 0);
    }
    if (kc < 7) {
#pragma unroll
      for (int i = 0; i < 4; ++i) {
        int u = i * 256 + t;
        int o = u >> 2, k16 = u & 3;
        *(short8*)(&Bnxt[o * 40 + k16 * 8]) = breg[i];
      }
    }
    __syncthreads();
  }

  int n = bx * 4 + wv;
#pragma unroll
  for (int ct = 0; ct < 16; ++ct) {
    int col = ct * 16 + lo;
    float b = bfold[col];
    float s = 0.f;
#pragma unroll
    for (int r = 0; r < 4; ++r) s += fmaxf(acc[ct][r] + b, 0.f);
    s += __shfl_xor(s, 16);
    s += __shfl_xor(s, 32);
    if (quad == 0) x0b[n * 256 + col] = f2bf(s * 0.0625f);
  }
}

// ---------------------------------------------------------------------------
// QKV MFMA + fused k_fill (blocks >= 768). B dbuf single-barrier.
// Q,K [h][n][32] (Q pre-scaled); V TRANSPOSED [h][d][n].
// ---------------------------------------------------------------------------
__global__ __launch_bounds__(256) void k_qkv(const u16* __restrict__ X,
    const u16* __restrict__ WB, const float* __restrict__ bias,
    u16* __restrict__ qb, u16* __restrict__ kb, u16* __restrict__ vb,
    const int* __restrict__ edges, const float* __restrict__ ew,
    const float* __restrict__ dinv, int* __restrict__ cursor,
    int* __restrict__ colidx, float* __restrict__ nval) {
  __shared__ u16 Al[16 * 264];
  __shared__ u16 Bl[2][256 * 40];
  int t = threadIdx.x;

  if (blockIdx.x >= 768) {              // fused k_fill
    int i = (blockIdx.x - 768) * 256 + t;
    int e = i & (NE - 1);
    int fwd = (i < NE);
    int a = edges[2 * e], b = edges[2 * e + 1];
    int row = fwd ? a : b, col = fwd ? b : a;
    float v = ew[e];
    int pos = atomicAdd(&cursor[row], 1);
    colidx[pos] = col;
    nval[pos] = dinv[row] * v * dinv[col];
    return;
  }

  int bx = blockIdx.x & 255, yb = blockIdx.x >> 8;
  int wv = t >> 6, ln = t & 63, lo = ln & 15, quad = ln >> 4;
  const u16* WBy = WB + yb * 65536;

#pragma unroll
  for (int i = 0; i < 2; ++i) {
    int fg = i * 256 + t;
    int node = fg >> 5, kq = fg & 31;
    short8 v = *(const short8*)(X + (bx * 16 + node) * 256 + kq * 8);
    *(short8*)(&Al[node * 264 + kq * 8]) = v;
  }
#pragma unroll
  for (int i = 0; i < 4; ++i) {
    int u = i * 256 + t;
    int o = u >> 2, k16 = u & 3;
    short8 v = *(const short8*)(WBy + o * 256 + k16 * 8);
    *(short8*)(&Bl[0][o * 40 + k16 * 8]) = v;
  }
  floatx4 acc[4];
#pragma unroll
  for (int i = 0; i < 4; ++i) acc[i] = (floatx4){0.f, 0.f, 0.f, 0.f};
  __syncthreads();

  for (int kc = 0; kc < 8; ++kc) {
    int cur = kc & 1;
    short8 breg[4];
    if (kc < 7) {
#pragma unroll
      for (int i = 0; i < 4; ++i) {
        int u = i * 256 + t;
        int o = u >> 2, k16 = u & 3;
        breg[i] = *(const short8*)(WBy + o * 256 + (kc + 1) * 32 + k16 * 8);
      }
    }
    short8 af = *(const short8*)(&Al[lo * 264 + kc * 32 + quad * 8]);
#pragma unroll
    for (int ci = 0; ci < 4; ++ci) {
      int ct = wv * 4 + ci;
      short8 bf = *(const short8*)(&Bl[cur][(ct * 16 + lo) * 40 + quad * 8]);
      acc[ci] = __builtin_amdgcn_mfma_f32_16x16x32_bf16(af, bf, acc[ci], 0, 0, 0);
    }
    if (kc < 7) {
#pragma unroll
      for (int i = 0; i < 4; ++i) {
        int u = i * 256 + t;
        int o = u >> 2, k16 = u & 3;
        *(short8*)(&Bl[cur ^ 1][o * 40 + k16 * 8]) = breg[i];
      }
    }
    __syncthreads();
  }
#pragma unroll
  for (int ci = 0; ci < 4; ++ci) {
    int jj = (wv * 4 + ci) * 16 + lo;
    int h = jj >> 5, d = jj & 31;
    float bj = bias[yb * 256 + jj];
#pragma unroll
    for (int r = 0; r < 4; ++r) {
      int n = bx * 16 + quad * 4 + r;
      float v = acc[ci][r] + bj;
      if (yb == 0)      qb[(h * 4096 + n) * 32 + d] = f2bf(v * QSCALE);
      else if (yb == 1) kb[(h * 4096 + n) * 32 + d] = f2bf(v);
      else              vb[(h * 32 + d) * 4096 + n] = f2bf(v);   // transposed
    }
  }
}

// ---------------------------------------------------------------------------
// Attention v6: split-K=8, 128-thread blocks (2 waves x 32 q), grid
// (64, 8, 8) = 4096 blocks -> 16 blocks/CU (100% static occupancy).
// Single P buffer per wave/qhalf (WAR hidden by 8 waves/SIMD).
// O and lsum accumulated with fp32 atomicAdd into pre-zeroed buffers.
// ---------------------------------------------------------------------------
__global__ __launch_bounds__(128) void k_attn(const u16* __restrict__ Q,
    const u16* __restrict__ K, const u16* __restrict__ VT,
    float* __restrict__ Oacc, float* __restrict__ lp) {
  __shared__ u32 Pl[2][2][16 * 36];    // [wave][qhalf][q=16][36]
  const int t = threadIdx.x;
  const int wv = t >> 6, ln = t & 63, lo = ln & 15, quad = ln >> 4;
  const int h = blockIdx.y, sp = blockIdx.z;
  const int qbase = blockIdx.x * 64 + wv * 32;

  short8 qf0 = *(const short8*)(Q + (size_t)(h * 4096 + qbase + lo) * 32 + quad * 8);
  short8 qf1 = *(const short8*)(Q + (size_t)(h * 4096 + qbase + 16 + lo) * 32 + quad * 8);

  const u16* Kh = K + (size_t)(h * 4096 + sp * 512) * 32;
  const u16* v0p = VT + (size_t)(h * 32 + lo) * 4096 + sp * 512;
  const u16* v1p = v0p + 16 * 4096;

  floatx4 o00 = {0.f,0.f,0.f,0.f}, o01 = {0.f,0.f,0.f,0.f};
  floatx4 o10 = {0.f,0.f,0.f,0.f}, o11 = {0.f,0.f,0.f,0.f};
  float ls0 = 0.f, ls1 = 0.f;
  const floatx4 z = {0.f, 0.f, 0.f, 0.f};

  short8 kf[4];
#pragma unroll
  for (int kbi = 0; kbi < 4; ++kbi)
    kf[kbi] = *(const short8*)(Kh + (kbi * 16 + lo) * 32 + quad * 8);

  for (int kt = 0; kt < 8; ++kt) {
    const int k0 = kt * 64;
    short8 vf00 = *(const short8*)(v0p + k0 + quad * 8);
    short8 vf01 = *(const short8*)(v0p + k0 + 32 + quad * 8);
    short8 vf10 = *(const short8*)(v1p + k0 + quad * 8);
    short8 vf11 = *(const short8*)(v1p + k0 + 32 + quad * 8);

    floatx4 s0[4], s1[4];
#pragma unroll
    for (int kbi = 0; kbi < 4; ++kbi) {
      s0[kbi] = __builtin_amdgcn_mfma_f32_16x16x32_bf16(kf[kbi], qf0, z, 0, 0, 0);
      s1[kbi] = __builtin_amdgcn_mfma_f32_16x16x32_bf16(kf[kbi], qf1, z, 0, 0, 0);
    }
    const int k0n = ((kt + 1) & 7) * 64;
#pragma unroll
    for (int kbi = 0; kbi < 4; ++kbi)
      kf[kbi] = *(const short8*)(Kh + (k0n + kbi * 16 + lo) * 32 + quad * 8);

    u32* Pw0 = &Pl[wv][0][lo * 36];
#pragma unroll
    for (int kbi = 0; kbi < 4; ++kbi) {
      float p0 = __builtin_amdgcn_exp2f(s0[kbi][0]);
      float p1 = __builtin_amdgcn_exp2f(s0[kbi][1]);
      float p2 = __builtin_amdgcn_exp2f(s0[kbi][2]);
      float p3 = __builtin_amdgcn_exp2f(s0[kbi][3]);
      ls0 += (p0 + p1) + (p2 + p3);
      Pw0[kbi * 8 + quad * 2]     = pkbf(p0, p1);
      Pw0[kbi * 8 + quad * 2 + 1] = pkbf(p2, p3);
    }
    u32* Pw1 = &Pl[wv][1][lo * 36];
#pragma unroll
    for (int kbi = 0; kbi < 4; ++kbi) {
      float p0 = __builtin_amdgcn_exp2f(s1[kbi][0]);
      float p1 = __builtin_amdgcn_exp2f(s1[kbi][1]);
      float p2 = __builtin_amdgcn_exp2f(s1[kbi][2]);
      float p3 = __builtin_amdgcn_exp2f(s1[kbi][3]);
      ls1 += (p0 + p1) + (p2 + p3);
      Pw1[kbi * 8 + quad * 2]     = pkbf(p0, p1);
      Pw1[kbi * 8 + quad * 2 + 1] = pkbf(p2, p3);
    }

    short8 pf00 = *(const short8*)(Pw0 + quad * 4);
    short8 pf01 = *(const short8*)(Pw0 + 16 + quad * 4);
    short8 pf10 = *(const short8*)(Pw1 + quad * 4);
    short8 pf11 = *(const short8*)(Pw1 + 16 + quad * 4);
    o00 = __builtin_amdgcn_mfma_f32_16x16x32_bf16(vf00, pf00, o00, 0, 0, 0);
    o00 = __builtin_amdgcn_mfma_f32_16x16x32_bf16(vf01, pf01, o00, 0, 0, 0);
    o01 = __builtin_amdgcn_mfma_f32_16x16x32_bf16(vf10, pf00, o01, 0, 0, 0);
    o01 = __builtin_amdgcn_mfma_f32_16x16x32_bf16(vf11, pf01, o01, 0, 0, 0);
    o10 = __builtin_amdgcn_mfma_f32_16x16x32_bf16(vf00, pf10, o10, 0, 0, 0);
    o10 = __builtin_amdgcn_mfma_f32_16x16x32_bf16(vf01, pf11, o10, 0, 0, 0);
    o11 = __builtin_amdgcn_mfma_f32_16x16x32_bf16(vf10, pf10, o11, 0, 0, 0);
    o11 = __builtin_amdgcn_mfma_f32_16x16x32_bf16(vf11, pf11, o11, 0, 0, 0);
  }

  ls0 += __shfl_xor(ls0, 16); ls0 += __shfl_xor(ls0, 32);
  ls1 += __shfl_xor(ls1, 16); ls1 += __shfl_xor(ls1, 32);

  const int fb = h * 32;
  const int nq0 = qbase + lo, nq1 = qbase + 16 + lo;
#pragma unroll
  for (int r = 0; r < 4; ++r) {
    atomicAdd(&Oacc[(size_t)nq0 * 256 + fb + quad * 4 + r], o00[r]);
    atomicAdd(&Oacc[(size_t)nq0 * 256 + fb + 16 + quad * 4 + r], o01[r]);
    atomicAdd(&Oacc[(size_t)nq1 * 256 + fb + quad * 4 + r], o10[r]);
    atomicAdd(&Oacc[(size_t)nq1 * 256 + fb + 16 + quad * 4 + r], o11[r]);
  }
  if (quad == 0) {
    atomicAdd(&lp[h * 4096 + nq0], ls0);
    atomicAdd(&lp[h * 4096 + nq1], ls1);
  }
}

// ---------------------------------------------------------------------------
// proj MFMA: A staged from Oacc/lp (divide by l), col-split x2, B dbuf,
// one barrier/chunk; out x1b BF16 [n][256].
// ---------------------------------------------------------------------------
__global__ __launch_bounds__(256) void k_proj(const float* __restrict__ Oacc,
    const float* __restrict__ lp, const u16* __restrict__ WB,
    const float* __restrict__ bias, u16* __restrict__ x1b) {
  __shared__ u16 Al[16 * 264];
  __shared__ u16 Bl[2][128 * 40];
  int t = threadIdx.x;
  int bx = blockIdx.x >> 1, ch = blockIdx.x & 1;
  int wv = t >> 6, ln = t & 63, lo = ln & 15, quad = ln >> 4;
  int nb = bx * 16;
  const u16* WBh = WB + ch * 128 * 256;
  int hh = t >> 5;

#pragma unroll
  for (int i = 0; i < 16; ++i) {
    float o = Oacc[(size_t)(nb + i) * 256 + t];
    float l = lp[hh * 4096 + nb + i];
    Al[i * 264 + t] = f2bf(o / l);
  }

#pragma unroll
  for (int i = 0; i < 2; ++i) {
    int u = i * 256 + t;
    int o = u >> 2, k16 = u & 3;
    short8 v = *(const short8*)(WBh + o * 256 + k16 * 8);
    *(short8*)(&Bl[0][o * 40 + k16 * 8]) = v;
  }
  floatx4 acc[2];
  acc[0] = (floatx4){0.f, 0.f, 0.f, 0.f};
  acc[1] = (floatx4){0.f, 0.f, 0.f, 0.f};
  __syncthreads();

  for (int kc = 0; kc < 8; ++kc) {
    int cur = kc & 1;
    short8 breg[2];
    if (kc < 7) {
#pragma unroll
      for (int i = 0; i < 2; ++i) {
        int u = i * 256 + t;
        int o = u >> 2, k16 = u & 3;
        breg[i] = *(const short8*)(WBh + o * 256 + (kc + 1) * 32 + k16 * 8);
      }
    }
    short8 af = *(const short8*)(&Al[lo * 264 + kc * 32 + quad * 8]);
#pragma unroll
    for (int ci = 0; ci < 2; ++ci) {
      int lc = (wv * 2 + ci) * 16 + lo;
      short8 bf = *(const short8*)(&Bl[cur][lc * 40 + quad * 8]);
      acc[ci] = __builtin_amdgcn_mfma_f32_16x16x32_bf16(af, bf, acc[ci], 0, 0, 0);
    }
    if (kc < 7) {
#pragma unroll
      for (int i = 0; i < 2; ++i) {
        int u = i * 256 + t;
        int o = u >> 2, k16 = u & 3;
        *(short8*)(&Bl[cur ^ 1][o * 40 + k16 * 8]) = breg[i];
      }
    }
    __syncthreads();
  }
#pragma unroll
  for (int ci = 0; ci < 2; ++ci) {
    int col = ch * 128 + (wv * 2 + ci) * 16 + lo;
    float bj = bias[col];
#pragma unroll
    for (int r = 0; r < 4; ++r) {
      int n = nb + quad * 4 + r;
      x1b[n * 256 + col] = f2bf(acc[ci][r] + bj);
    }
  }
}

// ---------------------------------------------------------------------------
// Graph scan (+dinv).
// ---------------------------------------------------------------------------
__global__ __launch_bounds__(1024) void k_scan(const int* __restrict__ cnt,
    const float* __restrict__ deg, int* __restrict__ rowptr,
    int* __restrict__ cursor, float* __restrict__ dinv) {
  __shared__ int part[1024];
  int t = threadIdx.x;
#pragma unroll
  for (int j = 0; j < 4; ++j) {
    int i = t * 4 + j;
    dinv[i] = 1.0f / sqrtf(deg[i] + 1e-6f);
  }
  int4 v = ((const int4*)cnt)[t];
  int tot = v.x + v.y + v.z + v.w;
  part[t] = tot;
  __syncthreads();
  for (int off = 1; off < 1024; off <<= 1) {
    int add = (t >= off) ? part[t - off] : 0;
    __syncthreads();
    part[t] += add;
    __syncthreads();
  }
  int base = part[t] - tot;
  int i0 = t * 4;
  int b0 = base, b1 = base + v.x, b2 = b1 + v.y, b3 = b2 + v.z;
  rowptr[i0] = b0; rowptr[i0 + 1] = b1; rowptr[i0 + 2] = b2; rowptr[i0 + 3] = b3;
  cursor[i0] = b0; cursor[i0 + 1] = b1; cursor[i0 + 2] = b2; cursor[i0 + 3] = b3;
  if (t == 1023) rowptr[4096] = part[1023];
}

// ---------------------------------------------------------------------------
// SpMM, bf16 gather: 2 rows/block, 128 threads/row, u32 = 2 feats/thread,
// 4-edge unroll. Out bf16 packed [n][256].
// ---------------------------------------------------------------------------
__global__ __launch_bounds__(256) void k_spmm(const int* __restrict__ rowptr,
    const int* __restrict__ colidx, const float* __restrict__ nval,
    const u16* __restrict__ xb, u16* __restrict__ yb_out) {
  int n = blockIdx.x * 2 + (threadIdx.x >> 7);
  int tf = (threadIdx.x & 127) * 2;
  int s = rowptr[n], e = rowptr[n + 1];
  float a0 = 0.f, a1 = 0.f;
  int j = s;
  for (; j + 4 <= e; j += 4) {
    int c0 = colidx[j], c1 = colidx[j + 1], c2 = colidx[j + 2], c3 = colidx[j + 3];
    float v0 = nval[j], v1 = nval[j + 1], v2 = nval[j + 2], v3 = nval[j + 3];
    u32 x0 = *(const u32*)(xb + c0 * 256 + tf);
    u32 x1 = *(const u32*)(xb + c1 * 256 + tf);
    u32 x2 = *(const u32*)(xb + c2 * 256 + tf);
    u32 x3 = *(const u32*)(xb + c3 * 256 + tf);
    a0 = fmaf(v0, bfasf((u16)(x0 & 0xffffu)), a0);
    a1 = fmaf(v0, bfasf((u16)(x0 >> 16)), a1);
    a0 = fmaf(v1, bfasf((u16)(x1 & 0xffffu)), a0);
    a1 = fmaf(v1, bfasf((u16)(x1 >> 16)), a1);
    a0 = fmaf(v2, bfasf((u16)(x2 & 0xffffu)), a0);
    a1 = fmaf(v2, bfasf((u16)(x2 >> 16)), a1);
    a0 = fmaf(v3, bfasf((u16)(x3 & 0xffffu)), a0);
    a1 = fmaf(v3, bfasf((u16)(x3 >> 16)), a1);
  }
  for (; j < e; ++j) {
    int c = colidx[j];
    float v = nval[j];
    u32 x0 = *(const u32*)(xb + c * 256 + tf);
    a0 = fmaf(v, bfasf((u16)(x0 & 0xffffu)), a0);
    a1 = fmaf(v, bfasf((u16)(x0 >> 16)), a1);
  }
  *(u32*)(yb_out + n * 256 + tf) = pkbf(a0, a1);
}

// ---------------------------------------------------------------------------
// GCN1 MFMA + bias + LN + relu; B dbuf single-barrier; writes g1b BF16.
// ---------------------------------------------------------------------------
__global__ __launch_bounds__(256) void k_gcn1(const u16* __restrict__ Yb,
    const u16* __restrict__ WB, const float* __restrict__ bias,
    const float* __restrict__ lng, const float* __restrict__ lnb,
    u16* __restrict__ g1b) {
  __shared__ u16 Al[16 * 264];
  __shared__ u16 Bl[2][256 * 40];
  __shared__ float redS[4][16], redQ[4][16];
  int t = threadIdx.x, bx = blockIdx.x;
  int wv = t >> 6, ln = t & 63, lo = ln & 15, quad = ln >> 4;
#pragma unroll
  for (int i = 0; i < 2; ++i) {
    int fg = i * 256 + t;
    int node = fg >> 5, kq = fg & 31;
    short8 v = *(const short8*)(Yb + (bx * 16 + node) * 256 + kq * 8);
    *(short8*)(&Al[node * 264 + kq * 8]) = v;
  }
#pragma unroll
  for (int i = 0; i < 4; ++i) {
    int u = i * 256 + t;
    int o = u >> 2, k16 = u & 3;
    short8 v = *(const short8*)(WB + o * 256 + k16 * 8);
    *(short8*)(&Bl[0][o * 40 + k16 * 8]) = v;
  }
  floatx4 acc[4];
#pragma unroll
  for (int i = 0; i < 4; ++i) acc[i] = (floatx4){0.f, 0.f, 0.f, 0.f};
  __syncthreads();

  for (int kc = 0; kc < 8; ++kc) {
    int cur = kc & 1;
    short8 breg[4];
    if (kc < 7) {
#pragma unroll
      for (int i = 0; i < 4; ++i) {
        int u = i * 256 + t;
        int o = u >> 2, k16 = u & 3;
        breg[i] = *(const short8*)(WB + o * 256 + (kc + 1) * 32 + k16 * 8);
      }
    }
    short8 af = *(const short8*)(&Al[lo * 264 + kc * 32 + quad * 8]);
#pragma unroll
    for (int ci = 0; ci < 4; ++ci) {
      int ct = wv * 4 + ci;
      short8 bf = *(const short8*)(&Bl[cur][(ct * 16 + lo) * 40 + quad * 8]);
      acc[ci] = __builtin_amdgcn_mfma_f32_16x16x32_bf16(af, bf, acc[ci], 0, 0, 0);
    }
    if (kc < 7) {
#pragma unroll
      for (int i = 0; i < 4; ++i) {
        int u = i * 256 + t;
        int o = u >> 2, k16 = u & 3;
        *(short8*)(&Bl[cur ^ 1][o * 40 + k16 * 8]) = breg[i];
      }
    }
    __syncthreads();
  }
  float val[4][4];
  float s1[4] = {0.f, 0.f, 0.f, 0.f}, s2[4] = {0.f, 0.f, 0.f, 0.f};
#pragma unroll
  for (int ci = 0; ci < 4; ++ci) {
    int col = (wv * 4 + ci) * 16 + lo;
    float bb = bias[col];
#pragma unroll
    for (int r = 0; r < 4; ++r) {
      float x = acc[ci][r] + bb;
      val[ci][r] = x;
      s1[r] += x; s2[r] += x * x;
    }
  }
#pragma unroll
  for (int r = 0; r < 4; ++r) {
#pragma unroll
    for (int msk = 1; msk < 16; msk <<= 1) {
      s1[r] += __shfl_xor(s1[r], msk);
      s2[r] += __shfl_xor(s2[r], msk);
    }
  }
  if (lo == 0) {
#pragma unroll
    for (int r = 0; r < 4; ++r) {
      redS[wv][quad * 4 + r] = s1[r];
      redQ[wv][quad * 4 + r] = s2[r];
    }
  }
  __syncthreads();
  float muR[4], rsR[4];
#pragma unroll
  for (int r = 0; r < 4; ++r) {
    int row = quad * 4 + r;
    float S1 = redS[0][row] + redS[1][row] + redS[2][row] + redS[3][row];
    float S2 = redQ[0][row] + redQ[1][row] + redQ[2][row] + redQ[3][row];
    float mu = S1 * (1.0f / 256.0f);
    float var = S2 * (1.0f / 256.0f) - mu * mu;
    muR[r] = mu;
    rsR[r] = 1.0f / sqrtf(var + 1e-5f);
  }
#pragma unroll
  for (int ci = 0; ci < 4; ++ci) {
    int col = (wv * 4 + ci) * 16 + lo;
    float gg = lng[col], bb = lnb[col];
#pragma unroll
    for (int r = 0; r < 4; ++r) {
      int n = bx * 16 + quad * 4 + r;
      g1b[n * 256 + col] = f2bf(fmaxf((val[ci][r] - muR[r]) * rsR[r] * gg + bb, 0.f));
    }
  }
}

// ---------------------------------------------------------------------------
// GCN2 + shortcut fused, B dbuf single-barrier -> out [4096][128].
// ---------------------------------------------------------------------------
__global__ __launch_bounds__(256) void k_gcn2(const u16* __restrict__ Yb,
    const u16* __restrict__ G1b, const u16* __restrict__ WB2,
    const float* __restrict__ b2, const u16* __restrict__ WBsc,
    const float* __restrict__ scb, const float* __restrict__ lng,
    const float* __restrict__ lnb, float* __restrict__ out) {
  __shared__ u16 Al[16 * 264];      // Yb (gcn2 A)
  __shared__ u16 Al2[16 * 264];     // G1 (sc A)
  __shared__ u16 Bl[2][128 * 40];   // gcn2 W dbuf
  __shared__ u16 Bl2[2][128 * 40];  // sc W dbuf
  __shared__ float redS[4][16], redQ[4][16];
  __shared__ float scbuf[16][128];
  int t = threadIdx.x, bx = blockIdx.x;
  int wv = t >> 6, ln = t & 63, lo = ln & 15, quad = ln >> 4;
#pragma unroll
  for (int i = 0; i < 2; ++i) {
    int fg = i * 256 + t;
    int node = fg >> 5, kq = fg & 31;
    short8 v = *(const short8*)(Yb + (bx * 16 + node) * 256 + kq * 8);
    *(short8*)(&Al[node * 264 + kq * 8]) = v;
    short8 v2 = *(const short8*)(G1b + (bx * 16 + node) * 256 + kq * 8);
    *(short8*)(&Al2[node * 264 + kq * 8]) = v2;
  }
#pragma unroll
  for (int i = 0; i < 2; ++i) {
    int u = i * 256 + t;
    int o = u >> 2, k16 = u & 3;
    short8 v = *(const short8*)(WB2 + o * 256 + k16 * 8);
    *(short8*)(&Bl[0][o * 40 + k16 * 8]) = v;
    short8 v2 = *(const short8*)(WBsc + o * 256 + k16 * 8);
    *(short8*)(&Bl2[0][o * 40 + k16 * 8]) = v2;
  }
  floatx4 accg[2], accs[2];
  accg[0] = (floatx4){0.f,0.f,0.f,0.f}; accg[1] = (floatx4){0.f,0.f,0.f,0.f};
  accs[0] = (floatx4){0.f,0.f,0.f,0.f}; accs[1] = (floatx4){0.f,0.f,0.f,0.f};
  __syncthreads();

  for (int kc = 0; kc < 8; ++kc) {
    int cur = kc & 1;
    short8 breg[2], breg2[2];
    if (kc < 7) {
#pragma unroll
      for (int i = 0; i < 2; ++i) {
        int u = i * 256 + t;
        int o = u >> 2, k16 = u & 3;
        breg[i]  = *(const short8*)(WB2 + o * 256 + (kc + 1) * 32 + k16 * 8);
        breg2[i] = *(const short8*)(WBsc + o * 256 + (kc + 1) * 32 + k16 * 8);
      }
    }
    short8 af  = *(const short8*)(&Al[lo * 264 + kc * 32 + quad * 8]);
    short8 af2 = *(const short8*)(&Al2[lo * 264 + kc * 32 + quad * 8]);
#pragma unroll
    for (int ci = 0; ci < 2; ++ci) {
      int ct = wv * 2 + ci;
      short8 bf  = *(const short8*)(&Bl[cur][(ct * 16 + lo) * 40 + quad * 8]);
      short8 bf2 = *(const short8*)(&Bl2[cur][(ct * 16 + lo) * 40 + quad * 8]);
      accg[ci] = __builtin_amdgcn_mfma_f32_16x16x32_bf16(af, bf, accg[ci], 0, 0, 0);
      accs[ci] = __builtin_amdgcn_mfma_f32_16x16x32_bf16(af2, bf2, accs[ci], 0, 0, 0);
    }
    if (kc < 7) {
#pragma unroll
      for (int i = 0; i < 2; ++i) {
        int u = i * 256 + t;
        int o = u >> 2, k16 = u & 3;
        *(short8*)(&Bl[cur ^ 1][o * 40 + k16 * 8])  = breg[i];
        *(short8*)(&Bl2[cur ^ 1][o * 40 + k16 * 8]) = breg2[i];
      }
    }
    __syncthreads();
  }
#pragma unroll
  for (int ci = 0; ci < 2; ++ci) {
    int col = (wv * 2 + ci) * 16 + lo;
    float bj = scb[col];
#pragma unroll
    for (int r = 0; r < 4; ++r)
      scbuf[quad * 4 + r][col] = accs[ci][r] + bj;
  }
  float val[2][4];
  float s1[4] = {0.f, 0.f, 0.f, 0.f}, s2[4] = {0.f, 0.f, 0.f, 0.f};
#pragma unroll
  for (int ci = 0; ci < 2; ++ci) {
    int col = (wv * 2 + ci) * 16 + lo;
    float bb = b2[col];
#pragma unroll
    for (int r = 0; r < 4; ++r) {
      float x = accg[ci][r] + bb;
      val[ci][r] = x;
      s1[r] += x; s2[r] += x * x;
    }
  }
#pragma unroll
  for (int r = 0; r < 4; ++r) {
#pragma unroll
    for (int msk = 1; msk < 16; msk <<= 1) {
      s1[r] += __shfl_xor(s1[r], msk);
      s2[r] += __shfl_xor(s2[r], msk);
    }
  }
  if (lo == 0) {
#pragma unroll
    for (int r = 0; r < 4; ++r) {
      redS[wv][quad * 4 + r] = s1[r];
      redQ[wv][quad * 4 + r] = s2[r];
    }
  }
  __syncthreads();
  float muR[4], rsR[4];
#pragma unroll
  for (int r = 0; r < 4; ++r) {
    int row = quad * 4 + r;
    float S1 = redS[0][row] + redS[1][row] + redS[2][row] + redS[3][row];
    float S2 = redQ[0][row] + redQ[1][row] + redQ[2][row] + redQ[3][row];
    float mu = S1 * (1.0f / 128.0f);
    float var = S2 * (1.0f / 128.0f) - mu * mu;
    muR[r] = mu;
    rsR[r] = 1.0f / sqrtf(var + 1e-5f);
  }
#pragma unroll
  for (int ci = 0; ci < 2; ++ci) {
    int col = (wv * 2 + ci) * 16 + lo;
    float gg = lng[col], bb = lnb[col];
#pragma unroll
    for (int r = 0; r < 4; ++r) {
      int n = bx * 16 + quad * 4 + r;
      float vv = fmaxf((val[ci][r] - muR[r]) * rsR[r] * gg + bb, 0.f);
      out[n * 128 + col] = vv + scbuf[quad * 4 + r][col];
    }
  }
}

// ---------------------------------------------------------------------------
extern "C" void kernel_launch(void* const* d_in, const int* in_sizes, int n_in,
                              void* d_out, int out_size, void* d_ws, size_t ws_size,
                              hipStream_t stream) {
  const float* node_feats = (const float*)d_in[0];
  const int* edges = (const int*)d_in[1];
  const float* eweights = (const float*)d_in[2];
  const float* conv_w = (const float*)d_in[3];
  const float* conv_b = (const float*)d_in[4];
  const float* bn_g = (const float*)d_in[5];
  const float* bn_b = (const float*)d_in[6];
  const float* bn_m = (const float*)d_in[7];
  const float* bn_v = (const float*)d_in[8];
  const float* qkv_w = (const float*)d_in[9];
  const float* qkv_bias = (const float*)d_in[10];
  const float* proj_w = (const float*)d_in[11];
  const float* proj_b = (const float*)d_in[12];
  const float* gcn1_w = (const float*)d_in[13];
  const float* gcn1_b = (const float*)d_in[14];
  const float* ln1_g = (const float*)d_in[15];
  const float* ln1_b = (const float*)d_in[16];
  const float* gcn2_w = (const float*)d_in[17];
  const float* gcn2_b = (const float*)d_in[18];
  const float* ln2_g = (const float*)d_in[19];
  const float* ln2_b = (const float*)d_in[20];
  const float* sc_w = (const float*)d_in[21];
  const float* sc_b = (const float*)d_in[22];
  float* out = (float*)d_out;

  float* w = (float*)d_ws;
  u16* WBc     = (u16*)(w + 0);          // 65536 u16
  float* bfold = w + 32768;              // 256 f
  u16* WBqkv   = (u16*)(w + 33024);      // 196608 u16
  u16* WBproj  = (u16*)(w + 131328);     // 65536 u16
  u16* WB1     = (u16*)(w + 164096);     // 65536 u16
  u16* WB2     = (u16*)(w + 196864);     // 32768 u16
  u16* WBsc    = (u16*)(w + 213248);     // 32768 u16
  u16* x0b     = (u16*)(w + 229632);     // 1048576 u16
  u16* qb      = (u16*)(w + 753920);     // 1048576 u16 each
  u16* kb      = qb + 1048576;
  u16* vb      = kb + 1048576;           // V TRANSPOSED [h][d][n]
  u16* x1b     = (u16*)(w + 753920);     // bf16 [n][256], aliases qb (dead)
  float* Oacc  = w + 2851072;            // 1048576 f (attn O accumulator)
  u16* y1b     = (u16*)(w + 2851072);    // bf16 [n][256] (spmm out, after proj)
  u16* g1b     = (u16*)(w + 3899648);    // bf16 [n][256] (gcn1 out)
  float* lp    = w + 4948224;            // 32768 f (l accumulator)
  float* deg   = w + 5472512;            // 4096 f
  int* cnt     = (int*)(w + 5476608);    // 4096
  float* dinv  = w + 5480704;            // 4096
  int* rowptr  = (int*)(w + 5484800);    // 4097 (+pad)
  int* cursor  = (int*)(w + 5488928);    // 4096
  int* colidx  = (int*)(w + 5493024);    // 131072
  float* nval  = w + 5624096;            // 131072

  (void)in_sizes; (void)n_in; (void)out_size; (void)ws_size;

  k_prep<<<1792, 256, 0, stream>>>(conv_w, conv_b, bn_g, bn_b, bn_m, bn_v,
                                   qkv_w, proj_w, gcn1_w, gcn2_w, sc_w,
                                   WBc, bfold, WBqkv, WBproj, WB1, WB2, WBsc,
                                   deg, cnt, Oacc, lp);
  k_conv<<<1536, 256, 0, stream>>>(node_feats, WBc, bfold, x0b,
                                   edges, eweights, cnt, deg);
  k_scan<<<1, 1024, 0, stream>>>(cnt, deg, rowptr, cursor, dinv);
  k_qkv<<<1280, 256, 0, stream>>>(x0b, WBqkv, qkv_bias, qb, kb, vb,
                                  edges, eweights, dinv, cursor, colidx, nval);
  k_attn<<<dim3(64, 8, 8), 128, 0, stream>>>(qb, kb, vb, Oacc, lp);
  k_proj<<<512, 256, 0, stream>>>(Oacc, lp, WBproj, proj_b, x1b);
  k_spmm<<<2048, 256, 0, stream>>>(rowptr, colidx, nval, x1b, y1b);
  k_gcn1<<<256, 256, 0, stream>>>(y1b, WB1, gcn1_b, ln1_g, ln1_b, g1b);
  k_spmm<<<2048, 256, 0, stream>>>(rowptr, colidx, nval, g1b, y1b);
  k_gcn2<<<256, 256, 0, stream>>>(y1b, g1b, WB2, gcn2_b, WBsc, sc_b,
                                  ln2_g, ln2_b, out);
}

// Round 14
// 284.064 us; speedup vs baseline: 1.2032x; 1.2032x over previous
//
#include <hip/hip_runtime.h>

// ---------------------------------------------------------------------------
// GraphEmbedding pipeline for MI355X (gfx950) — round 14:
//  - full revert to round-12 structure (atomic split-K=8 regressed: 132 MB
//    of write-through atomic traffic)
//  - k_attn: P-pair stores merged into ds_write_b64 (breaks the 4-way
//    even-bank write conflict pattern; 8 instead of 16 write ops/tile)
// N=4096, IN_DIM=256, HID=256, OUT=128, HEADS=8, HD=32, E=65536
// ---------------------------------------------------------------------------

#define NN 4096
#define NE 65536

typedef unsigned short u16;
typedef unsigned int u32;
typedef __attribute__((ext_vector_type(2))) unsigned int u32x2;
typedef __attribute__((ext_vector_type(8))) short short8;   // 8 x bf16
typedef __attribute__((ext_vector_type(4))) short bhalf4;   // 4 x bf16
typedef __attribute__((ext_vector_type(4))) float floatx4;

#define QSCALE (0.17677669529663687f * 1.4426950408889634f)  // hd^-0.5 * log2(e)

__device__ __forceinline__ u32 fasu(float x) {
  union { float f; u32 u; } v; v.f = x; return v.u;
}
__device__ __forceinline__ float bfasf(u16 h) {
  union { float f; u32 u; } v; v.u = ((u32)h) << 16; return v.f;
}
__device__ __forceinline__ u16 f2bf(float x) {
  u32 u = fasu(x);
  return (u16)((u + 0x7FFFu + ((u >> 16) & 1u)) >> 16);
}
// pack two fp32 -> bf16 pair (round-half-up) in one v_perm
__device__ __forceinline__ u32 pkbf(float lo, float hi) {
  return __builtin_amdgcn_perm(fasu(hi) + 0x8000u, fasu(lo) + 0x8000u,
                               0x07060302u);
}

// ---------------------------------------------------------------------------
// Prep: fold BN into conv weights; convert all GEMM weights to bf16 [o][c];
// zero deg/cnt.
// ---------------------------------------------------------------------------
__global__ __launch_bounds__(256) void k_prep(
    const float* __restrict__ conv_w, const float* __restrict__ conv_b,
    const float* __restrict__ bn_g, const float* __restrict__ bn_b,
    const float* __restrict__ bn_m, const float* __restrict__ bn_v,
    const float* __restrict__ qkv_w, const float* __restrict__ proj_w,
    const float* __restrict__ gcn1_w, const float* __restrict__ gcn2_w,
    const float* __restrict__ sc_w,
    u16* __restrict__ WBc, float* __restrict__ bfold,
    u16* __restrict__ WBqkv, u16* __restrict__ WBproj,
    u16* __restrict__ WB1, u16* __restrict__ WB2, u16* __restrict__ WBsc,
    float* __restrict__ deg, int* __restrict__ cnt) {
  int g = blockIdx.x * 256 + threadIdx.x;
  if (g < 4096) { deg[g] = 0.f; cnt[g] = 0; }
  if (g < 65536) {                      // conv fold: [o][c]
    int o = g >> 8;
    float alpha = bn_g[o] / sqrtf(bn_v[o] + 1e-5f);
    WBc[g] = f2bf(conv_w[g] * alpha);
    if ((g & 255) == 0) bfold[o] = (conv_b[o] - bn_m[o]) * alpha + bn_b[o];
  } else if (g < 262144) {
    int g2 = g - 65536;  WBqkv[g2] = f2bf(qkv_w[g2]);
  } else if (g < 327680) {
    int g3 = g - 262144; WBproj[g3] = f2bf(proj_w[g3]);
  } else if (g < 393216) {
    int g4 = g - 327680; WB1[g4] = f2bf(gcn1_w[g4]);
  } else if (g < 425984) {
    int g5 = g - 393216; WB2[g5] = f2bf(gcn2_w[g5]);
  } else if (g < 458752) {
    int g6 = g - 425984; WBsc[g6] = f2bf(sc_w[g6]);
  }
}

// ---------------------------------------------------------------------------
// Conv 1x1 + BN + relu + spatial mean, MFMA (round-11 version, unchanged).
// ---------------------------------------------------------------------------
__global__ __launch_bounds__(256, 3) void k_conv(const float* __restrict__ F,
    const u16* __restrict__ WB, const float* __restrict__ bfold,
    u16* __restrict__ x0b,
    const int* __restrict__ edges, const float* __restrict__ ew,
    int* __restrict__ cnt, float* __restrict__ deg) {
  __shared__ u16 smem[20480];           // 2 x (256 rows x 40 u16) = 40 KB
  int t = threadIdx.x, bx = blockIdx.x;

  if (bx >= 1024) {                     // fused k_count
    int i = (bx - 1024) * 256 + t;      // 0..2E-1
    int e = i & (NE - 1);
    int fwd = (i < NE);
    int a = edges[2 * e], b = edges[2 * e + 1];
    int row = fwd ? a : b;
    float v = ew[e];
    atomicAdd(&cnt[row], 1);
    atomicAdd(&deg[row], v);
    return;
  }

  int wv = t >> 6, ln = t & 63, lo = ln & 15, quad = ln >> 4;

  const float* Fn = F + (size_t)(bx * 4 + wv) * 4096;
  short8 afr[8];
#pragma unroll
  for (int half = 0; half < 2; ++half) {
    float tmp[32];
#pragma unroll
    for (int kc2 = 0; kc2 < 4; ++kc2) {
      int cb = (half * 4 + kc2) * 32 + quad * 8;
#pragma unroll
      for (int j = 0; j < 8; ++j)
        tmp[kc2 * 8 + j] = Fn[(cb + j) * 16 + lo];
    }
#pragma unroll
    for (int kc2 = 0; kc2 < 4; ++kc2)
#pragma unroll
      for (int j = 0; j < 8; ++j)
        afr[half * 4 + kc2][j] = (short)f2bf(tmp[kc2 * 8 + j]);
  }

#pragma unroll
  for (int i = 0; i < 4; ++i) {
    int u = i * 256 + t;
    int o = u >> 2, k16 = u & 3;
    short8 v = *(const short8*)(WB + o * 256 + k16 * 8);
    *(short8*)(&smem[o * 40 + k16 * 8]) = v;
  }

  floatx4 acc[16];
#pragma unroll
  for (int i = 0; i < 16; ++i) acc[i] = (floatx4){0.f, 0.f, 0.f, 0.f};

  __syncthreads();

  for (int kc = 0; kc < 8; ++kc) {
    int cur = kc & 1;
    u16* Bcur = smem + cur * 10240;
    u16* Bnxt = smem + (cur ^ 1) * 10240;
    short8 breg[4];
    if (kc < 7) {
#pragma unroll
      for (int i = 0; i < 4; ++i) {
        int u = i * 256 + t;
        int o = u >> 2, k16 = u & 3;
        breg[i] = *(const short8*)(WB + o * 256 + (kc + 1) * 32 + k16 * 8);
      }
    }
#pragma unroll
    for (int ct = 0; ct < 16; ++ct) {
      short8 bf = *(const short8*)(Bcur + (ct * 16 + lo) * 40 + quad * 8);
      acc[ct] = __builtin_amdgcn_mfma_f32_16x16x32_bf16(afr[kc], bf, acc[ct], 0, 0, 0);
    }
    if (kc < 7) {
#pragma unroll
      for (int i = 0; i < 4; ++i) {
        int u = i * 256 + t;
        int o = u >> 2, k16 = u & 3;
        *(short8*)(&Bnxt[o * 40 + k16 * 8]) = breg[i];
      }
    }
    __syncthreads();
  }

  int n = bx * 4 + wv;
#pragma unroll
  for (int ct = 0; ct < 16; ++ct) {
    int col = ct * 16 + lo;
    float b = bfold[col];
    float s = 0.f;
#pragma unroll
    for (int r = 0; r < 4; ++r) s += fmaxf(acc[ct][r] + b, 0.f);
    s += __shfl_xor(s, 16);
    s += __shfl_xor(s, 32);
    if (quad == 0) x0b[n * 256 + col] = f2bf(s * 0.0625f);
  }
}

// ---------------------------------------------------------------------------
// QKV MFMA + fused k_fill (blocks >= 768). B dbuf single-barrier.
// Q,K [h][n][32] (Q pre-scaled); V TRANSPOSED [h][d][n].
// ---------------------------------------------------------------------------
__global__ __launch_bounds__(256) void k_qkv(const u16* __restrict__ X,
    const u16* __restrict__ WB, const float* __restrict__ bias,
    u16* __restrict__ qb, u16* __restrict__ kb, u16* __restrict__ vb,
    const int* __restrict__ edges, const float* __restrict__ ew,
    const float* __restrict__ dinv, int* __restrict__ cursor,
    int* __restrict__ colidx, float* __restrict__ nval) {
  __shared__ u16 Al[16 * 264];
  __shared__ u16 Bl[2][256 * 40];
  int t = threadIdx.x;

  if (blockIdx.x >= 768) {              // fused k_fill
    int i = (blockIdx.x - 768) * 256 + t;
    int e = i & (NE - 1);
    int fwd = (i < NE);
    int a = edges[2 * e], b = edges[2 * e + 1];
    int row = fwd ? a : b, col = fwd ? b : a;
    float v = ew[e];
    int pos = atomicAdd(&cursor[row], 1);
    colidx[pos] = col;
    nval[pos] = dinv[row] * v * dinv[col];
    return;
  }

  int bx = blockIdx.x & 255, yb = blockIdx.x >> 8;
  int wv = t >> 6, ln = t & 63, lo = ln & 15, quad = ln >> 4;
  const u16* WBy = WB + yb * 65536;

#pragma unroll
  for (int i = 0; i < 2; ++i) {
    int fg = i * 256 + t;
    int node = fg >> 5, kq = fg & 31;
    short8 v = *(const short8*)(X + (bx * 16 + node) * 256 + kq * 8);
    *(short8*)(&Al[node * 264 + kq * 8]) = v;
  }
#pragma unroll
  for (int i = 0; i < 4; ++i) {
    int u = i * 256 + t;
    int o = u >> 2, k16 = u & 3;
    short8 v = *(const short8*)(WBy + o * 256 + k16 * 8);
    *(short8*)(&Bl[0][o * 40 + k16 * 8]) = v;
  }
  floatx4 acc[4];
#pragma unroll
  for (int i = 0; i < 4; ++i) acc[i] = (floatx4){0.f, 0.f, 0.f, 0.f};
  __syncthreads();

  for (int kc = 0; kc < 8; ++kc) {
    int cur = kc & 1;
    short8 breg[4];
    if (kc < 7) {
#pragma unroll
      for (int i = 0; i < 4; ++i) {
        int u = i * 256 + t;
        int o = u >> 2, k16 = u & 3;
        breg[i] = *(const short8*)(WBy + o * 256 + (kc + 1) * 32 + k16 * 8);
      }
    }
    short8 af = *(const short8*)(&Al[lo * 264 + kc * 32 + quad * 8]);
#pragma unroll
    for (int ci = 0; ci < 4; ++ci) {
      int ct = wv * 4 + ci;
      short8 bf = *(const short8*)(&Bl[cur][(ct * 16 + lo) * 40 + quad * 8]);
      acc[ci] = __builtin_amdgcn_mfma_f32_16x16x32_bf16(af, bf, acc[ci], 0, 0, 0);
    }
    if (kc < 7) {
#pragma unroll
      for (int i = 0; i < 4; ++i) {
        int u = i * 256 + t;
        int o = u >> 2, k16 = u & 3;
        *(short8*)(&Bl[cur ^ 1][o * 40 + k16 * 8]) = breg[i];
      }
    }
    __syncthreads();
  }
#pragma unroll
  for (int ci = 0; ci < 4; ++ci) {
    int jj = (wv * 4 + ci) * 16 + lo;
    int h = jj >> 5, d = jj & 31;
    float bj = bias[yb * 256 + jj];
#pragma unroll
    for (int r = 0; r < 4; ++r) {
      int n = bx * 16 + quad * 4 + r;
      float v = acc[ci][r] + bj;
      if (yb == 0)      qb[(h * 4096 + n) * 32 + d] = f2bf(v * QSCALE);
      else if (yb == 1) kb[(h * 4096 + n) * 32 + d] = f2bf(v);
      else              vb[(h * 32 + d) * 4096 + n] = f2bf(v);   // transposed
    }
  }
}

// ---------------------------------------------------------------------------
// Attention (round-12 structure — 32 q/wave, split-K=4, double-buffered P,
// K prefetch) with P-pair stores merged into 8-byte writes.
// ---------------------------------------------------------------------------
__global__ __launch_bounds__(256) void k_attn(const u16* __restrict__ Q,
    const u16* __restrict__ K, const u16* __restrict__ VT,
    u16* __restrict__ OTp, float* __restrict__ lp) {
  __shared__ u32 Pl[4][2][2][16 * 36];   // [wave][buf][qhalf][q=16][36]
  const int t = threadIdx.x;
  const int wv = t >> 6, ln = t & 63, lo = ln & 15, quad = ln >> 4;
  const int h = blockIdx.y, sp = blockIdx.z;
  const int qbase = blockIdx.x * 128 + wv * 32;

  short8 qf0 = *(const short8*)(Q + (size_t)(h * 4096 + qbase + lo) * 32 + quad * 8);
  short8 qf1 = *(const short8*)(Q + (size_t)(h * 4096 + qbase + 16 + lo) * 32 + quad * 8);

  const u16* Kh = K + (size_t)(h * 4096 + sp * 1024) * 32;
  const u16* v0p = VT + (size_t)(h * 32 + lo) * 4096 + sp * 1024;
  const u16* v1p = v0p + 16 * 4096;

  floatx4 o00 = {0.f,0.f,0.f,0.f}, o01 = {0.f,0.f,0.f,0.f};
  floatx4 o10 = {0.f,0.f,0.f,0.f}, o11 = {0.f,0.f,0.f,0.f};
  float ls0 = 0.f, ls1 = 0.f;
  const floatx4 z = {0.f, 0.f, 0.f, 0.f};

  short8 kf[4];
#pragma unroll
  for (int kbi = 0; kbi < 4; ++kbi)
    kf[kbi] = *(const short8*)(Kh + (kbi * 16 + lo) * 32 + quad * 8);

  for (int kt = 0; kt < 16; ++kt) {
    const int k0 = kt * 64;
    const int cur = kt & 1;
    short8 vf00 = *(const short8*)(v0p + k0 + quad * 8);
    short8 vf01 = *(const short8*)(v0p + k0 + 32 + quad * 8);
    short8 vf10 = *(const short8*)(v1p + k0 + quad * 8);
    short8 vf11 = *(const short8*)(v1p + k0 + 32 + quad * 8);

    floatx4 s0[4], s1[4];
#pragma unroll
    for (int kbi = 0; kbi < 4; ++kbi) {
      s0[kbi] = __builtin_amdgcn_mfma_f32_16x16x32_bf16(kf[kbi], qf0, z, 0, 0, 0);
      s1[kbi] = __builtin_amdgcn_mfma_f32_16x16x32_bf16(kf[kbi], qf1, z, 0, 0, 0);
    }
    const int k0n = ((kt + 1) & 15) * 64;
#pragma unroll
    for (int kbi = 0; kbi < 4; ++kbi)
      kf[kbi] = *(const short8*)(Kh + (k0n + kbi * 16 + lo) * 32 + quad * 8);

    u32* Pw0 = &Pl[wv][cur][0][lo * 36];
#pragma unroll
    for (int kbi = 0; kbi < 4; ++kbi) {
      float p0 = __builtin_amdgcn_exp2f(s0[kbi][0]);
      float p1 = __builtin_amdgcn_exp2f(s0[kbi][1]);
      float p2 = __builtin_amdgcn_exp2f(s0[kbi][2]);
      float p3 = __builtin_amdgcn_exp2f(s0[kbi][3]);
      ls0 += (p0 + p1) + (p2 + p3);
      u32x2 pw; pw[0] = pkbf(p0, p1); pw[1] = pkbf(p2, p3);
      *(u32x2*)(Pw0 + kbi * 8 + quad * 2) = pw;     // one ds_write_b64
    }
    u32* Pw1 = &Pl[wv][cur][1][lo * 36];
#pragma unroll
    for (int kbi = 0; kbi < 4; ++kbi) {
      float p0 = __builtin_amdgcn_exp2f(s1[kbi][0]);
      float p1 = __builtin_amdgcn_exp2f(s1[kbi][1]);
      float p2 = __builtin_amdgcn_exp2f(s1[kbi][2]);
      float p3 = __builtin_amdgcn_exp2f(s1[kbi][3]);
      ls1 += (p0 + p1) + (p2 + p3);
      u32x2 pw; pw[0] = pkbf(p0, p1); pw[1] = pkbf(p2, p3);
      *(u32x2*)(Pw1 + kbi * 8 + quad * 2) = pw;
    }

    short8 pf00 = *(const short8*)(Pw0 + quad * 4);
    short8 pf01 = *(const short8*)(Pw0 + 16 + quad * 4);
    short8 pf10 = *(const short8*)(Pw1 + quad * 4);
    short8 pf11 = *(const short8*)(Pw1 + 16 + quad * 4);
    o00 = __builtin_amdgcn_mfma_f32_16x16x32_bf16(vf00, pf00, o00, 0, 0, 0);
    o00 = __builtin_amdgcn_mfma_f32_16x16x32_bf16(vf01, pf01, o00, 0, 0, 0);
    o01 = __builtin_amdgcn_mfma_f32_16x16x32_bf16(vf10, pf00, o01, 0, 0, 0);
    o01 = __builtin_amdgcn_mfma_f32_16x16x32_bf16(vf11, pf01, o01, 0, 0, 0);
    o10 = __builtin_amdgcn_mfma_f32_16x16x32_bf16(vf00, pf10, o10, 0, 0, 0);
    o10 = __builtin_amdgcn_mfma_f32_16x16x32_bf16(vf01, pf11, o10, 0, 0, 0);
    o11 = __builtin_amdgcn_mfma_f32_16x16x32_bf16(vf10, pf10, o11, 0, 0, 0);
    o11 = __builtin_amdgcn_mfma_f32_16x16x32_bf16(vf11, pf11, o11, 0, 0, 0);
  }

  ls0 += __shfl_xor(ls0, 16); ls0 += __shfl_xor(ls0, 32);
  ls1 += __shfl_xor(ls1, 16); ls1 += __shfl_xor(ls1, 32);

  const int fb = sp * 256 + h * 32;
  const int nq0 = qbase + lo, nq1 = qbase + 16 + lo;
#pragma unroll
  for (int r = 0; r < 4; ++r) {
    OTp[(size_t)(fb + quad * 4 + r) * 4096 + nq0]      = f2bf(o00[r]);
    OTp[(size_t)(fb + 16 + quad * 4 + r) * 4096 + nq0] = f2bf(o01[r]);
    OTp[(size_t)(fb + quad * 4 + r) * 4096 + nq1]      = f2bf(o10[r]);
    OTp[(size_t)(fb + 16 + quad * 4 + r) * 4096 + nq1] = f2bf(o11[r]);
  }
  if (quad == 0) {
    lp[(sp * 8 + h) * 4096 + nq0] = ls0;
    lp[(sp * 8 + h) * 4096 + nq1] = ls1;
  }
}

// ---------------------------------------------------------------------------
// proj MFMA fused with split-K combine. Col-split x2: grid 512; B dbuf,
// one barrier/chunk; out x1b BF16 [n][256].
// ---------------------------------------------------------------------------
__global__ __launch_bounds__(256) void k_proj(const u16* __restrict__ OTp,
    const float* __restrict__ lp, const u16* __restrict__ WB,
    const float* __restrict__ bias, u16* __restrict__ x1b) {
  __shared__ u16 Al[16 * 264];
  __shared__ u16 Bl[2][128 * 40];
  int t = threadIdx.x;
  int bx = blockIdx.x >> 1, ch = blockIdx.x & 1;
  int wv = t >> 6, ln = t & 63, lo = ln & 15, quad = ln >> 4;
  int nb = bx * 16;
  const u16* WBh = WB + ch * 128 * 256;

  float a16[16];
#pragma unroll
  for (int i = 0; i < 16; ++i) a16[i] = 0.f;
#pragma unroll
  for (int sp = 0; sp < 4; ++sp) {
    const u16* base = OTp + ((size_t)(sp * 256 + t)) * 4096 + nb;
    short8 v0 = *(const short8*)(base);
    short8 v1 = *(const short8*)(base + 8);
#pragma unroll
    for (int j = 0; j < 8; ++j) {
      a16[j]     += bfasf((u16)v0[j]);
      a16[8 + j] += bfasf((u16)v1[j]);
    }
  }
  int hh = t >> 5;
  float lt[16];
#pragma unroll
  for (int i = 0; i < 16; ++i) lt[i] = 0.f;
#pragma unroll
  for (int sp = 0; sp < 4; ++sp) {
    const float* lbase = lp + (sp * 8 + hh) * 4096 + nb;
#pragma unroll
    for (int q4 = 0; q4 < 4; ++q4) {
      float4 a = *(const float4*)(lbase + q4 * 4);
      lt[q4 * 4 + 0] += a.x; lt[q4 * 4 + 1] += a.y;
      lt[q4 * 4 + 2] += a.z; lt[q4 * 4 + 3] += a.w;
    }
  }
#pragma unroll
  for (int i = 0; i < 16; ++i)
    Al[i * 264 + t] = f2bf(a16[i] / lt[i]);

#pragma unroll
  for (int i = 0; i < 2; ++i) {
    int u = i * 256 + t;
    int o = u >> 2, k16 = u & 3;
    short8 v = *(const short8*)(WBh + o * 256 + k16 * 8);
    *(short8*)(&Bl[0][o * 40 + k16 * 8]) = v;
  }
  floatx4 acc[2];
  acc[0] = (floatx4){0.f, 0.f, 0.f, 0.f};
  acc[1] = (floatx4){0.f, 0.f, 0.f, 0.f};
  __syncthreads();

  for (int kc = 0; kc < 8; ++kc) {
    int cur = kc & 1;
    short8 breg[2];
    if (kc < 7) {
#pragma unroll
      for (int i = 0; i < 2; ++i) {
        int u = i * 256 + t;
        int o = u >> 2, k16 = u & 3;
        breg[i] = *(const short8*)(WBh + o * 256 + (kc + 1) * 32 + k16 * 8);
      }
    }
    short8 af = *(const short8*)(&Al[lo * 264 + kc * 32 + quad * 8]);
#pragma unroll
    for (int ci = 0; ci < 2; ++ci) {
      int lc = (wv * 2 + ci) * 16 + lo;
      short8 bf = *(const short8*)(&Bl[cur][lc * 40 + quad * 8]);
      acc[ci] = __builtin_amdgcn_mfma_f32_16x16x32_bf16(af, bf, acc[ci], 0, 0, 0);
    }
    if (kc < 7) {
#pragma unroll
      for (int i = 0; i < 2; ++i) {
        int u = i * 256 + t;
        int o = u >> 2, k16 = u & 3;
        *(short8*)(&Bl[cur ^ 1][o * 40 + k16 * 8]) = breg[i];
      }
    }
    __syncthreads();
  }
#pragma unroll
  for (int ci = 0; ci < 2; ++ci) {
    int col = ch * 128 + (wv * 2 + ci) * 16 + lo;
    float bj = bias[col];
#pragma unroll
    for (int r = 0; r < 4; ++r) {
      int n = nb + quad * 4 + r;
      x1b[n * 256 + col] = f2bf(acc[ci][r] + bj);
    }
  }
}

// ---------------------------------------------------------------------------
// Graph scan (+dinv).
// ---------------------------------------------------------------------------
__global__ __launch_bounds__(1024) void k_scan(const int* __restrict__ cnt,
    const float* __restrict__ deg, int* __restrict__ rowptr,
    int* __restrict__ cursor, float* __restrict__ dinv) {
  __shared__ int part[1024];
  int t = threadIdx.x;
#pragma unroll
  for (int j = 0; j < 4; ++j) {
    int i = t * 4 + j;
    dinv[i] = 1.0f / sqrtf(deg[i] + 1e-6f);
  }
  int4 v = ((const int4*)cnt)[t];
  int tot = v.x + v.y + v.z + v.w;
  part[t] = tot;
  __syncthreads();
  for (int off = 1; off < 1024; off <<= 1) {
    int add = (t >= off) ? part[t - off] : 0;
    __syncthreads();
    part[t] += add;
    __syncthreads();
  }
  int base = part[t] - tot;
  int i0 = t * 4;
  int b0 = base, b1 = base + v.x, b2 = b1 + v.y, b3 = b2 + v.z;
  rowptr[i0] = b0; rowptr[i0 + 1] = b1; rowptr[i0 + 2] = b2; rowptr[i0 + 3] = b3;
  cursor[i0] = b0; cursor[i0 + 1] = b1; cursor[i0 + 2] = b2; cursor[i0 + 3] = b3;
  if (t == 1023) rowptr[4096] = part[1023];
}

// ---------------------------------------------------------------------------
// SpMM, bf16 gather: 2 rows/block, 128 threads/row, u32 = 2 feats/thread,
// 4-edge unroll. Out bf16 packed [n][256].
// ---------------------------------------------------------------------------
__global__ __launch_bounds__(256) void k_spmm(const int* __restrict__ rowptr,
    const int* __restrict__ colidx, const float* __restrict__ nval,
    const u16* __restrict__ xb, u16* __restrict__ yb_out) {
  int n = blockIdx.x * 2 + (threadIdx.x >> 7);
  int tf = (threadIdx.x & 127) * 2;
  int s = rowptr[n], e = rowptr[n + 1];
  float a0 = 0.f, a1 = 0.f;
  int j = s;
  for (; j + 4 <= e; j += 4) {
    int c0 = colidx[j], c1 = colidx[j + 1], c2 = colidx[j + 2], c3 = colidx[j + 3];
    float v0 = nval[j], v1 = nval[j + 1], v2 = nval[j + 2], v3 = nval[j + 3];
    u32 x0 = *(const u32*)(xb + c0 * 256 + tf);
    u32 x1 = *(const u32*)(xb + c1 * 256 + tf);
    u32 x2 = *(const u32*)(xb + c2 * 256 + tf);
    u32 x3 = *(const u32*)(xb + c3 * 256 + tf);
    a0 = fmaf(v0, bfasf((u16)(x0 & 0xffffu)), a0);
    a1 = fmaf(v0, bfasf((u16)(x0 >> 16)), a1);
    a0 = fmaf(v1, bfasf((u16)(x1 & 0xffffu)), a0);
    a1 = fmaf(v1, bfasf((u16)(x1 >> 16)), a1);
    a0 = fmaf(v2, bfasf((u16)(x2 & 0xffffu)), a0);
    a1 = fmaf(v2, bfasf((u16)(x2 >> 16)), a1);
    a0 = fmaf(v3, bfasf((u16)(x3 & 0xffffu)), a0);
    a1 = fmaf(v3, bfasf((u16)(x3 >> 16)), a1);
  }
  for (; j < e; ++j) {
    int c = colidx[j];
    float v = nval[j];
    u32 x0 = *(const u32*)(xb + c * 256 + tf);
    a0 = fmaf(v, bfasf((u16)(x0 & 0xffffu)), a0);
    a1 = fmaf(v, bfasf((u16)(x0 >> 16)), a1);
  }
  *(u32*)(yb_out + n * 256 + tf) = pkbf(a0, a1);
}

// ---------------------------------------------------------------------------
// GCN1 MFMA + bias + LN + relu; B dbuf single-barrier; writes g1b BF16.
// ---------------------------------------------------------------------------
__global__ __launch_bounds__(256) void k_gcn1(const u16* __restrict__ Yb,
    const u16* __restrict__ WB, const float* __restrict__ bias,
    const float* __restrict__ lng, const float* __restrict__ lnb,
    u16* __restrict__ g1b) {
  __shared__ u16 Al[16 * 264];
  __shared__ u16 Bl[2][256 * 40];
  __shared__ float redS[4][16], redQ[4][16];
  int t = threadIdx.x, bx = blockIdx.x;
  int wv = t >> 6, ln = t & 63, lo = ln & 15, quad = ln >> 4;
#pragma unroll
  for (int i = 0; i < 2; ++i) {
    int fg = i * 256 + t;
    int node = fg >> 5, kq = fg & 31;
    short8 v = *(const short8*)(Yb + (bx * 16 + node) * 256 + kq * 8);
    *(short8*)(&Al[node * 264 + kq * 8]) = v;
  }
#pragma unroll
  for (int i = 0; i < 4; ++i) {
    int u = i * 256 + t;
    int o = u >> 2, k16 = u & 3;
    short8 v = *(const short8*)(WB + o * 256 + k16 * 8);
    *(short8*)(&Bl[0][o * 40 + k16 * 8]) = v;
  }
  floatx4 acc[4];
#pragma unroll
  for (int i = 0; i < 4; ++i) acc[i] = (floatx4){0.f, 0.f, 0.f, 0.f};
  __syncthreads();

  for (int kc = 0; kc < 8; ++kc) {
    int cur = kc & 1;
    short8 breg[4];
    if (kc < 7) {
#pragma unroll
      for (int i = 0; i < 4; ++i) {
        int u = i * 256 + t;
        int o = u >> 2, k16 = u & 3;
        breg[i] = *(const short8*)(WB + o * 256 + (kc + 1) * 32 + k16 * 8);
      }
    }
    short8 af = *(const short8*)(&Al[lo * 264 + kc * 32 + quad * 8]);
#pragma unroll
    for (int ci = 0; ci < 4; ++ci) {
      int ct = wv * 4 + ci;
      short8 bf = *(const short8*)(&Bl[cur][(ct * 16 + lo) * 40 + quad * 8]);
      acc[ci] = __builtin_amdgcn_mfma_f32_16x16x32_bf16(af, bf, acc[ci], 0, 0, 0);
    }
    if (kc < 7) {
#pragma unroll
      for (int i = 0; i < 4; ++i) {
        int u = i * 256 + t;
        int o = u >> 2, k16 = u & 3;
        *(short8*)(&Bl[cur ^ 1][o * 40 + k16 * 8]) = breg[i];
      }
    }
    __syncthreads();
  }
  float val[4][4];
  float s1[4] = {0.f, 0.f, 0.f, 0.f}, s2[4] = {0.f, 0.f, 0.f, 0.f};
#pragma unroll
  for (int ci = 0; ci < 4; ++ci) {
    int col = (wv * 4 + ci) * 16 + lo;
    float bb = bias[col];
#pragma unroll
    for (int r = 0; r < 4; ++r) {
      float x = acc[ci][r] + bb;
      val[ci][r] = x;
      s1[r] += x; s2[r] += x * x;
    }
  }
#pragma unroll
  for (int r = 0; r < 4; ++r) {
#pragma unroll
    for (int msk = 1; msk < 16; msk <<= 1) {
      s1[r] += __shfl_xor(s1[r], msk);
      s2[r] += __shfl_xor(s2[r], msk);
    }
  }
  if (lo == 0) {
#pragma unroll
    for (int r = 0; r < 4; ++r) {
      redS[wv][quad * 4 + r] = s1[r];
      redQ[wv][quad * 4 + r] = s2[r];
    }
  }
  __syncthreads();
  float muR[4], rsR[4];
#pragma unroll
  for (int r = 0; r < 4; ++r) {
    int row = quad * 4 + r;
    float S1 = redS[0][row] + redS[1][row] + redS[2][row] + redS[3][row];
    float S2 = redQ[0][row] + redQ[1][row] + redQ[2][row] + redQ[3][row];
    float mu = S1 * (1.0f / 256.0f);
    float var = S2 * (1.0f / 256.0f) - mu * mu;
    muR[r] = mu;
    rsR[r] = 1.0f / sqrtf(var + 1e-5f);
  }
#pragma unroll
  for (int ci = 0; ci < 4; ++ci) {
    int col = (wv * 4 + ci) * 16 + lo;
    float gg = lng[col], bb = lnb[col];
#pragma unroll
    for (int r = 0; r < 4; ++r) {
      int n = bx * 16 + quad * 4 + r;
      g1b[n * 256 + col] = f2bf(fmaxf((val[ci][r] - muR[r]) * rsR[r] * gg + bb, 0.f));
    }
  }
}

// ---------------------------------------------------------------------------
// GCN2 + shortcut fused, B dbuf single-barrier -> out [4096][128].
// ---------------------------------------------------------------------------
__global__ __launch_bounds__(256) void k_gcn2(const u16* __restrict__ Yb,
    const u16* __restrict__ G1b, const u16* __restrict__ WB2,
    const float* __restrict__ b2, const u16* __restrict__ WBsc,
    const float* __restrict__ scb, const float* __restrict__ lng,
    const float* __restrict__ lnb, float* __restrict__ out) {
  __shared__ u16 Al[16 * 264];      // Yb (gcn2 A)
  __shared__ u16 Al2[16 * 264];     // G1 (sc A)
  __shared__ u16 Bl[2][128 * 40];   // gcn2 W dbuf
  __shared__ u16 Bl2[2][128 * 40];  // sc W dbuf
  __shared__ float redS[4][16], redQ[4][16];
  __shared__ float scbuf[16][128];
  int t = threadIdx.x, bx = blockIdx.x;
  int wv = t >> 6, ln = t & 63, lo = ln & 15, quad = ln >> 4;
#pragma unroll
  for (int i = 0; i < 2; ++i) {
    int fg = i * 256 + t;
    int node = fg >> 5, kq = fg & 31;
    short8 v = *(const short8*)(Yb + (bx * 16 + node) * 256 + kq * 8);
    *(short8*)(&Al[node * 264 + kq * 8]) = v;
    short8 v2 = *(const short8*)(G1b + (bx * 16 + node) * 256 + kq * 8);
    *(short8*)(&Al2[node * 264 + kq * 8]) = v2;
  }
#pragma unroll
  for (int i = 0; i < 2; ++i) {
    int u = i * 256 + t;
    int o = u >> 2, k16 = u & 3;
    short8 v = *(const short8*)(WB2 + o * 256 + k16 * 8);
    *(short8*)(&Bl[0][o * 40 + k16 * 8]) = v;
    short8 v2 = *(const short8*)(WBsc + o * 256 + k16 * 8);
    *(short8*)(&Bl2[0][o * 40 + k16 * 8]) = v2;
  }
  floatx4 accg[2], accs[2];
  accg[0] = (floatx4){0.f,0.f,0.f,0.f}; accg[1] = (floatx4){0.f,0.f,0.f,0.f};
  accs[0] = (floatx4){0.f,0.f,0.f,0.f}; accs[1] = (floatx4){0.f,0.f,0.f,0.f};
  __syncthreads();

  for (int kc = 0; kc < 8; ++kc) {
    int cur = kc & 1;
    short8 breg[2], breg2[2];
    if (kc < 7) {
#pragma unroll
      for (int i = 0; i < 2; ++i) {
        int u = i * 256 + t;
        int o = u >> 2, k16 = u & 3;
        breg[i]  = *(const short8*)(WB2 + o * 256 + (kc + 1) * 32 + k16 * 8);
        breg2[i] = *(const short8*)(WBsc + o * 256 + (kc + 1) * 32 + k16 * 8);
      }
    }
    short8 af  = *(const short8*)(&Al[lo * 264 + kc * 32 + quad * 8]);
    short8 af2 = *(const short8*)(&Al2[lo * 264 + kc * 32 + quad * 8]);
#pragma unroll
    for (int ci = 0; ci < 2; ++ci) {
      int ct = wv * 2 + ci;
      short8 bf  = *(const short8*)(&Bl[cur][(ct * 16 + lo) * 40 + quad * 8]);
      short8 bf2 = *(const short8*)(&Bl2[cur][(ct * 16 + lo) * 40 + quad * 8]);
      accg[ci] = __builtin_amdgcn_mfma_f32_16x16x32_bf16(af, bf, accg[ci], 0, 0, 0);
      accs[ci] = __builtin_amdgcn_mfma_f32_16x16x32_bf16(af2, bf2, accs[ci], 0, 0, 0);
    }
    if (kc < 7) {
#pragma unroll
      for (int i = 0; i < 2; ++i) {
        int u = i * 256 + t;
        int o = u >> 2, k16 = u & 3;
        *(short8*)(&Bl[cur ^ 1][o * 40 + k16 * 8])  = breg[i];
        *(short8*)(&Bl2[cur ^ 1][o * 40 + k16 * 8]) = breg2[i];
      }
    }
    __syncthreads();
  }
#pragma unroll
  for (int ci = 0; ci < 2; ++ci) {
    int col = (wv * 2 + ci) * 16 + lo;
    float bj = scb[col];
#pragma unroll
    for (int r = 0; r < 4; ++r)
      scbuf[quad * 4 + r][col] = accs[ci][r] + bj;
  }
  float val[2][4];
  float s1[4] = {0.f, 0.f, 0.f, 0.f}, s2[4] = {0.f, 0.f, 0.f, 0.f};
#pragma unroll
  for (int ci = 0; ci < 2; ++ci) {
    int col = (wv * 2 + ci) * 16 + lo;
    float bb = b2[col];
#pragma unroll
    for (int r = 0; r < 4; ++r) {
      float x = accg[ci][r] + bb;
      val[ci][r] = x;
      s1[r] += x; s2[r] += x * x;
    }
  }
#pragma unroll
  for (int r = 0; r < 4; ++r) {
#pragma unroll
    for (int msk = 1; msk < 16; msk <<= 1) {
      s1[r] += __shfl_xor(s1[r], msk);
      s2[r] += __shfl_xor(s2[r], msk);
    }
  }
  if (lo == 0) {
#pragma unroll
    for (int r = 0; r < 4; ++r) {
      redS[wv][quad * 4 + r] = s1[r];
      redQ[wv][quad * 4 + r] = s2[r];
    }
  }
  __syncthreads();
  float muR[4], rsR[4];
#pragma unroll
  for (int r = 0; r < 4; ++r) {
    int row = quad * 4 + r;
    float S1 = redS[0][row] + redS[1][row] + redS[2][row] + redS[3][row];
    float S2 = redQ[0][row] + redQ[1][row] + redQ[2][row] + redQ[3][row];
    float mu = S1 * (1.0f / 128.0f);
    float var = S2 * (1.0f / 128.0f) - mu * mu;
    muR[r] = mu;
    rsR[r] = 1.0f / sqrtf(var + 1e-5f);
  }
#pragma unroll
  for (int ci = 0; ci < 2; ++ci) {
    int col = (wv * 2 + ci) * 16 + lo;
    float gg = lng[col], bb = lnb[col];
#pragma unroll
    for (int r = 0; r < 4; ++r) {
      int n = bx * 16 + quad * 4 + r;
      float vv = fmaxf((val[ci][r] - muR[r]) * rsR[r] * gg + bb, 0.f);
      out[n * 128 + col] = vv + scbuf[quad * 4 + r][col];
    }
  }
}

// ---------------------------------------------------------------------------
extern "C" void kernel_launch(void* const* d_in, const int* in_sizes, int n_in,
                              void* d_out, int out_size, void* d_ws, size_t ws_size,
                              hipStream_t stream) {
  const float* node_feats = (const float*)d_in[0];
  const int* edges = (const int*)d_in[1];
  const float* eweights = (const float*)d_in[2];
  const float* conv_w = (const float*)d_in[3];
  const float* conv_b = (const float*)d_in[4];
  const float* bn_g = (const float*)d_in[5];
  const float* bn_b = (const float*)d_in[6];
  const float* bn_m = (const float*)d_in[7];
  const float* bn_v = (const float*)d_in[8];
  const float* qkv_w = (const float*)d_in[9];
  const float* qkv_bias = (const float*)d_in[10];
  const float* proj_w = (const float*)d_in[11];
  const float* proj_b = (const float*)d_in[12];
  const float* gcn1_w = (const float*)d_in[13];
  const float* gcn1_b = (const float*)d_in[14];
  const float* ln1_g = (const float*)d_in[15];
  const float* ln1_b = (const float*)d_in[16];
  const float* gcn2_w = (const float*)d_in[17];
  const float* gcn2_b = (const float*)d_in[18];
  const float* ln2_g = (const float*)d_in[19];
  const float* ln2_b = (const float*)d_in[20];
  const float* sc_w = (const float*)d_in[21];
  const float* sc_b = (const float*)d_in[22];
  float* out = (float*)d_out;

  float* w = (float*)d_ws;
  u16* WBc     = (u16*)(w + 0);          // 65536 u16
  float* bfold = w + 32768;              // 256 f
  u16* WBqkv   = (u16*)(w + 33024);      // 196608 u16
  u16* WBproj  = (u16*)(w + 131328);     // 65536 u16
  u16* WB1     = (u16*)(w + 164096);     // 65536 u16
  u16* WB2     = (u16*)(w + 196864);     // 32768 u16
  u16* WBsc    = (u16*)(w + 213248);     // 32768 u16
  u16* x0b     = (u16*)(w + 229632);     // 1048576 u16
  u16* qb      = (u16*)(w + 753920);     // 1048576 u16 each
  u16* kb      = qb + 1048576;
  u16* vb      = kb + 1048576;           // V TRANSPOSED [h][d][n]
  u16* x1b     = (u16*)(w + 753920);     // bf16 [n][256], aliases qb (dead)
  u16* y1b     = (u16*)(w + 2851072);    // bf16 [n][256] (spmm out)
  u16* g1b     = (u16*)(w + 3899648);    // bf16 [n][256] (gcn1 out)
  u16* OTp     = (u16*)(w + 2851072);    // 4x2MB bf16 partials (dead after proj)
  float* lp    = w + 4948224;            // 131072 f (l partials)
  float* deg   = w + 5472512;            // 4096 f
  int* cnt     = (int*)(w + 5476608);    // 4096
  float* dinv  = w + 5480704;            // 4096
  int* rowptr  = (int*)(w + 5484800);    // 4097 (+pad)
  int* cursor  = (int*)(w + 5488928);    // 4096
  int* colidx  = (int*)(w + 5493024);    // 131072
  float* nval  = w + 5624096;            // 131072

  (void)in_sizes; (void)n_in; (void)out_size; (void)ws_size;

  k_prep<<<1792, 256, 0, stream>>>(conv_w, conv_b, bn_g, bn_b, bn_m, bn_v,
                                   qkv_w, proj_w, gcn1_w, gcn2_w, sc_w,
                                   WBc, bfold, WBqkv, WBproj, WB1, WB2, WBsc,
                                   deg, cnt);
  k_conv<<<1536, 256, 0, stream>>>(node_feats, WBc, bfold, x0b,
                                   edges, eweights, cnt, deg);
  k_scan<<<1, 1024, 0, stream>>>(cnt, deg, rowptr, cursor, dinv);
  k_qkv<<<1280, 256, 0, stream>>>(x0b, WBqkv, qkv_bias, qb, kb, vb,
                                  edges, eweights, dinv, cursor, colidx, nval);
  k_attn<<<dim3(32, 8, 4), 256, 0, stream>>>(qb, kb, vb, OTp, lp);
  k_proj<<<512, 256, 0, stream>>>(OTp, lp, WBproj, proj_b, x1b);
  k_spmm<<<2048, 256, 0, stream>>>(rowptr, colidx, nval, x1b, y1b);
  k_gcn1<<<256, 256, 0, stream>>>(y1b, WB1, gcn1_b, ln1_g, ln1_b, g1b);
  k_spmm<<<2048, 256, 0, stream>>>(rowptr, colidx, nval, g1b, y1b);
  k_gcn2<<<256, 256, 0, stream>>>(y1b, g1b, WB2, gcn2_b, WBsc, sc_b,
                                  ln2_g, ln2_b, out);
}